// Round 7
// baseline (493.188 us; speedup 1.0000x reference)
//
#include <hip/hip_runtime.h>

// =====================================================================
// GraphAutoEncoder forward. GCN via CSR build + gather (unchanged).
// R14/R15: MFMA GEMM with LDS A-staging stuck at MfmaUtil ~6%,
// VALUBusy 17%, Occ 14% -> LATENCY-bound: 391-block grids (1.5/CU),
// barrier-serialized k-steps, B loads issued right before use, K tiny.
// R16: barrier-free GEMM. ALL activations carried as pre-split bf16
// hi/lo planes (producers' epilogues split; same bytes as fp32, same
// numerics as in-kernel split). GEMM main loop = pure global->VGPR
// loads + MFMA, no LDS at all. 128-thr blocks, wave tile 32x64, BM=64
// -> 782-3128 blocks (12-24 waves/CU). enc1 splits fp32 x in regs.
// =====================================================================

constexpr int NBLK = 128;           // scatter blocks (chunk = E/128)
constexpr int GRP  = NBLK / 8;      // block-groups per XCD residue

typedef __attribute__((ext_vector_type(8))) short bf16x8;
typedef __attribute__((ext_vector_type(4))) float f32x4;

// split two fp32 into packed-bf16 hi pair + lo pair (truncation split;
// hi = top 16 bits, lo = bf16(f - hi), residual <= 2^-16 |f|)
__device__ inline void split2(float f0, float f1, unsigned& hp, unsigned& lp) {
    unsigned u0 = __float_as_uint(f0), u1 = __float_as_uint(f1);
    hp = (u1 & 0xFFFF0000u) | (u0 >> 16);
    float r0 = f0 - __uint_as_float(u0 & 0xFFFF0000u);
    float r1 = f1 - __uint_as_float(u1 & 0xFFFF0000u);
    lp = (__float_as_uint(r1) & 0xFFFF0000u) | (__float_as_uint(r0) >> 16);
}

struct Bf16Pair { bf16x8 h, l; };
__device__ inline Bf16Pair split8(float4 a, float4 b) {
    union { unsigned u[4]; bf16x8 v; } H, L;
    split2(a.x, a.y, H.u[0], L.u[0]);
    split2(a.z, a.w, H.u[1], L.u[1]);
    split2(b.x, b.y, H.u[2], L.u[2]);
    split2(b.z, b.w, H.u[3], L.u[3]);
    Bf16Pair p; p.h = H.v; p.l = L.v; return p;
}

// ---------------- weight pre-split: fp32 -> bf16 hi/lo planes --------
struct WSplitArgs {
    const float* src[6];
    unsigned short* hi[6];
    unsigned short* lo[6];
    int n[6];
};
__global__ __launch_bounds__(256) void split_w(WSplitArgs a) {
    const int L = blockIdx.y;
    const int i = blockIdx.x * 256 + threadIdx.x;
    if (i < a.n[L]) {
        float f = a.src[L][i];
        unsigned u = __float_as_uint(f);
        float r = f - __uint_as_float(u & 0xFFFF0000u);
        a.hi[L][i] = (unsigned short)(u >> 16);
        a.lo[L][i] = (unsigned short)(__float_as_uint(r) >> 16);
    }
}

// ---------------- GEMM: barrier-free, LDS-free, planes in/out --------
// C[:,foff:+64] = act(A @ W^T + b). 128 thr = 2 waves stacked in M.
// Wave tile 32x64 (MF=2, NF=4). BM=64. grid = (ceil(N/64), M/64).
// A: either pre-split planes (Ahp/Alp) or fp32 (Af, AF32=true).
// OUT: 0 = fp32 C, 1 = bf16 hi/lo planes.
template <int K, int M, int ACT, bool BIAS, bool AF32, int OUT>
__global__ __launch_bounds__(128) void gemm_pp(
        const unsigned short* __restrict__ Ahp,
        const unsigned short* __restrict__ Alp,
        const float* __restrict__ Af,
        const unsigned short* __restrict__ Whp,
        const unsigned short* __restrict__ Wlp,
        const float* __restrict__ bias,
        float* __restrict__ Cf,
        unsigned short* __restrict__ Chi,
        unsigned short* __restrict__ Clo, int N) {
    static_assert(K % 32 == 0, "K%32");
    constexpr int MF = 2;
    constexpr int NF = 4;

    const int tid  = threadIdx.x;
    const int lane = tid & 63;
    const int wid  = tid >> 6;                    // 0..1
    const int fr   = lane & 15;
    const int fg   = lane >> 4;
    const int rowBase = blockIdx.x * 64 + wid * 32;
    const int foff    = blockIdx.y * 64;

    f32x4 acc[MF][NF];
#pragma unroll
    for (int mf = 0; mf < MF; ++mf)
#pragma unroll
        for (int nf = 0; nf < NF; ++nf) acc[mf][nf] = (f32x4)0.f;

    // clamped A rows (OOB rows produce garbage only in discarded outputs)
    int arow[MF];
#pragma unroll
    for (int mf = 0; mf < MF; ++mf) {
        int r = rowBase + mf * 16 + fr;
        arow[mf] = (r < N) ? r : (N - 1);
    }

#pragma unroll 2
    for (int kf = 0; kf < K / 32; ++kf) {
        const int ko = kf * 32 + fg * 8;
        bf16x8 ah[MF], al[MF], bh[NF], bl[NF];
#pragma unroll
        for (int mf = 0; mf < MF; ++mf) {
            if constexpr (AF32) {
                const float* ap = Af + (size_t)arow[mf] * K + ko;
                float4 f0 = *(const float4*)(ap);
                float4 f1 = *(const float4*)(ap + 4);
                Bf16Pair p = split8(f0, f1);
                ah[mf] = p.h; al[mf] = p.l;
            } else {
                const size_t ao = (size_t)arow[mf] * K + ko;
                ah[mf] = *(const bf16x8*)(Ahp + ao);
                al[mf] = *(const bf16x8*)(Alp + ao);
            }
        }
#pragma unroll
        for (int nf = 0; nf < NF; ++nf) {
            const size_t wo = (size_t)(foff + nf * 16 + fr) * K + ko;
            bh[nf] = *(const bf16x8*)(Whp + wo);
            bl[nf] = *(const bf16x8*)(Wlp + wo);
        }
#pragma unroll
        for (int mf = 0; mf < MF; ++mf)
#pragma unroll
            for (int nf = 0; nf < NF; ++nf) {
                acc[mf][nf] = __builtin_amdgcn_mfma_f32_16x16x32_bf16(
                    ah[mf], bh[nf], acc[mf][nf], 0, 0, 0);
                acc[mf][nf] = __builtin_amdgcn_mfma_f32_16x16x32_bf16(
                    al[mf], bh[nf], acc[mf][nf], 0, 0, 0);
                acc[mf][nf] = __builtin_amdgcn_mfma_f32_16x16x32_bf16(
                    ah[mf], bl[nf], acc[mf][nf], 0, 0, 0);
            }
    }

    // epilogue: D[row=(lane>>4)*4+i][col=lane&15] per frag
#pragma unroll
    for (int nf = 0; nf < NF; ++nf) {
        const int feat = foff + nf * 16 + fr;
        const float bv = BIAS ? bias[feat] : 0.f;
#pragma unroll
        for (int mf = 0; mf < MF; ++mf) {
            const int node0 = rowBase + mf * 16 + fg * 4;
#pragma unroll
            for (int i = 0; i < 4; ++i) {
                const int node = node0 + i;
                if (node < N) {
                    float x = acc[mf][nf][i] + bv;
                    if constexpr (ACT == 1) x = fmaxf(x, 0.f);
                    if constexpr (ACT == 2) x = 1.f / (1.f + __expf(-x));
                    const size_t idx = (size_t)node * M + feat;
                    if constexpr (OUT == 0) {
                        Cf[idx] = x;
                    } else {
                        unsigned u = __float_as_uint(x);
                        Chi[idx] = (unsigned short)(u >> 16);
                        float r = x - __uint_as_float(u & 0xFFFF0000u);
                        Clo[idx] = (unsigned short)(__float_as_uint(r) >> 16);
                    }
                }
            }
        }
    }
}

// ---------------- CSR build: deterministic counting sort -------------
// bucket b = dst >> 6; count index = b*128 + r*16 + g  (r = blockIdx&7,
// g = blockIdx>>3) => bucketBase[b] = pos[b*128]. Zero global atomics.

__global__ __launch_bounds__(256) void count_k(const int* __restrict__ ei,
                                               int* __restrict__ cnt,
                                               int NB, int E) {
    __shared__ int hist[784];
    const int tid = threadIdx.x;
    for (int i = tid; i < NB; i += 256) hist[i] = 0;
    __syncthreads();
    const int chunk = (E + NBLK - 1) / NBLK;
    const int lo = blockIdx.x * chunk;
    const int hi = min(lo + chunk, E);
    for (int e = lo + tid; e < hi; e += 256) {
        int d = ei[E + e];
        atomicAdd(&hist[d >> 6], 1);
    }
    __syncthreads();
    const int r = blockIdx.x & 7, g = blockIdx.x >> 3;
    for (int i = tid; i < NB; i += 256)
        cnt[i * NBLK + r * GRP + g] = hist[i];
}

__global__ __launch_bounds__(256) void scan1(const int* __restrict__ cnt,
                                             int* __restrict__ pos,
                                             int* __restrict__ bs, int n) {
    __shared__ int s[256];
    const int t = threadIdx.x;
    const int i0 = blockIdx.x * 512 + 2 * t;
    int c0 = (i0     < n) ? cnt[i0]     : 0;
    int c1 = (i0 + 1 < n) ? cnt[i0 + 1] : 0;
    int c = c0 + c1;
    s[t] = c;
    __syncthreads();
    for (int off = 1; off < 256; off <<= 1) {
        int v = (t >= off) ? s[t - off] : 0;
        __syncthreads();
        s[t] += v;
        __syncthreads();
    }
    int excl = s[t] - c;
    if (i0     < n) pos[i0]     = excl;
    if (i0 + 1 < n) pos[i0 + 1] = excl + c0;
    if (t == 255) bs[blockIdx.x] = s[255];
}

__global__ __launch_bounds__(256) void scan_tops(int* __restrict__ bs, int nb) {
    __shared__ int s[256];
    int t = threadIdx.x;
    int v = (t < nb) ? bs[t] : 0;
    s[t] = v;
    __syncthreads();
    for (int off = 1; off < 256; off <<= 1) {
        int u = (t >= off) ? s[t - off] : 0;
        __syncthreads();
        s[t] += u;
        __syncthreads();
    }
    if (t < nb) bs[t] = s[t] - v;
}

__global__ __launch_bounds__(256) void scan2(int* __restrict__ pos,
                                             const int* __restrict__ bs,
                                             int* __restrict__ bucketBase,
                                             int n, int NB, int E) {
    const int t = threadIdx.x;
    const int i0 = blockIdx.x * 512 + 2 * t;
    const int add = bs[blockIdx.x];
#pragma unroll
    for (int c = 0; c < 2; ++c) {
        int i = i0 + c;
        if (i < n) {
            int v = pos[i] + add;
            pos[i] = v;
            if ((i & (NBLK - 1)) == 0) bucketBase[i >> 7] = v;
        }
    }
    if (blockIdx.x == 0 && t == 0) bucketBase[NB] = E;
}

__global__ __launch_bounds__(256) void place_k(const int* __restrict__ ei,
                                               const float* __restrict__ w,
                                               const int* __restrict__ pos,
                                               int2* __restrict__ ebuf,
                                               int NB, int E) {
    __shared__ int cur[784];
    const int tid = threadIdx.x;
    const int r = blockIdx.x & 7, g = blockIdx.x >> 3;
    for (int i = tid; i < NB; i += 256) cur[i] = pos[i * NBLK + r * GRP + g];
    __syncthreads();
    const int chunk = (E + NBLK - 1) / NBLK;
    const int lo = blockIdx.x * chunk;
    const int hi = min(lo + chunk, E);
    for (int e = lo + tid; e < hi; e += 256) {
        int s = ei[e];
        int d = ei[E + e];
        float wv = w[e];
        int p = atomicAdd(&cur[d >> 6], 1);  // LDS atomic
        ebuf[p] = make_int2(s | ((d & 63) << 26), __float_as_int(wv));
    }
}

__global__ __launch_bounds__(256) void bucket_build(const int2* __restrict__ ebuf,
                                                    const int* __restrict__ bucketBase,
                                                    int2* __restrict__ sn,
                                                    int* __restrict__ row,
                                                    float* __restrict__ dinv,
                                                    int N, int E) {
    __shared__ int   lh[64];
    __shared__ float ldg[64];
    __shared__ int   sc[64];
    __shared__ int   lofs[64];
    const int tid  = threadIdx.x;
    const int base = bucketBase[blockIdx.x];
    const int end  = bucketBase[blockIdx.x + 1];

    if (tid < 64) { lh[tid] = 0; ldg[tid] = 0.f; }
    __syncthreads();
    for (int i = base + tid; i < end; i += 256) {
        int2 v = ebuf[i];
        int dl = ((unsigned)v.x) >> 26;
        atomicAdd(&lh[dl], 1);
        atomicAdd(&ldg[dl], __int_as_float(v.y));
    }
    __syncthreads();
    if (tid < 64) sc[tid] = lh[tid];
    __syncthreads();
    for (int off = 1; off < 64; off <<= 1) {
        int v = (tid < 64 && tid >= off) ? sc[tid - off] : 0;
        __syncthreads();
        if (tid < 64) sc[tid] += v;
        __syncthreads();
    }
    if (tid < 64) {
        int excl = sc[tid] - lh[tid];
        int d = (blockIdx.x << 6) + tid;
        if (d < N) {
            row[d]  = base + excl;
            dinv[d] = rsqrtf(fmaxf(1.0f + ldg[tid], 1e-12f));  // + self-loop
        }
        lofs[tid] = base + excl;
    }
    __syncthreads();
    for (int i = base + tid; i < end; i += 256) {
        int2 v = ebuf[i];
        unsigned u = (unsigned)v.x;
        int dl = u >> 26;
        int s  = u & 0x03FFFFFF;
        int p  = atomicAdd(&lofs[dl], 1);
        sn[p] = make_int2(s, v.y);
    }
    if (blockIdx.x == 0 && tid == 0) row[N] = E;
}

// payload.y <- w * dinv[src]
__global__ __launch_bounds__(256) void scale_pay(int2* __restrict__ sn,
                                                 const float* __restrict__ dinv,
                                                 int E) {
    int p = blockIdx.x * 256 + threadIdx.x;
    if (p < E) {
        int2 v = sn[p];
        sn[p] = make_int2(v.x, __float_as_int(__int_as_float(v.y) * dinv[v.x]));
    }
}

// ---------------- fused GCN aggregation (gather, no atomics) ---------
// g[i] = relu( (sum_e pay_e*t[src_e] + t[i]*dinv[i]) * dinv[i] + b )
// output written as bf16 hi/lo planes (consumed by next MFMA GEMM).
__global__ __launch_bounds__(256) void gcn_agg(const float* __restrict__ t,
                                               const int2* __restrict__ sn,
                                               const int* __restrict__ row,
                                               const float* __restrict__ dinv,
                                               const float* __restrict__ bias,
                                               unsigned short* __restrict__ outh,
                                               unsigned short* __restrict__ outl,
                                               int N) {
    const int lane = threadIdx.x & 63;
    int i = __builtin_amdgcn_readfirstlane((int)(blockIdx.x * 4) + (threadIdx.x >> 6));
    if (i >= N) return;
    float di   = dinv[i];
    float self = t[(size_t)i * 64 + lane];
    float acc  = 0.f;
    int p  = row[i];
    int pe = row[i + 1];
    for (; p + 4 <= pe; p += 4) {
        int2 v0 = sn[p];
        int2 v1 = sn[p + 1];
        int2 v2 = sn[p + 2];
        int2 v3 = sn[p + 3];
        acc += t[(size_t)v0.x * 64 + lane] * __int_as_float(v0.y);
        acc += t[(size_t)v1.x * 64 + lane] * __int_as_float(v1.y);
        acc += t[(size_t)v2.x * 64 + lane] * __int_as_float(v2.y);
        acc += t[(size_t)v3.x * 64 + lane] * __int_as_float(v3.y);
    }
    for (; p < pe; ++p) {
        int2 v = sn[p];
        acc += t[(size_t)v.x * 64 + lane] * __int_as_float(v.y);
    }
    float x = fmaxf((acc + self * di) * di + bias[lane], 0.f);
    const size_t idx = (size_t)i * 64 + lane;
    unsigned u = __float_as_uint(x);
    outh[idx] = (unsigned short)(u >> 16);
    float r = x - __uint_as_float(u & 0xFFFF0000u);
    outl[idx] = (unsigned short)(__float_as_uint(r) >> 16);
}

// =====================================================================
extern "C" void kernel_launch(void* const* d_in, const int* in_sizes, int n_in,
                              void* d_out, int out_size, void* d_ws, size_t ws_size,
                              hipStream_t stream) {
    const float* x      = (const float*)d_in[0];
    const int*   ei     = (const int*)d_in[1];   // int32 per harness contract
    const float* ew     = (const float*)d_in[2];
    const float* enc1_w = (const float*)d_in[3];
    const float* enc1_b = (const float*)d_in[4];
    const float* enc2_w = (const float*)d_in[5];
    const float* enc2_b = (const float*)d_in[6];
    const float* gcn1_w = (const float*)d_in[7];
    const float* gcn1_b = (const float*)d_in[8];
    const float* gcn2_w = (const float*)d_in[9];
    const float* gcn2_b = (const float*)d_in[10];
    const float* dec1_w = (const float*)d_in[11];
    const float* dec1_b = (const float*)d_in[12];
    const float* dec2_w = (const float*)d_in[13];
    const float* dec2_b = (const float*)d_in[14];

    const int N  = in_sizes[0] / 256;    // 50000
    const int E  = in_sizes[2];          // 1600000
    const int NB = (N + 63) / 64;        // 782 buckets
    const int NCNT = NB * NBLK;          // 100096 counters
    const int NS   = (NCNT + 511) / 512; // 196 scan blocks

    // workspace (~53 MB), lifetime-aliased:
    //  bufT [N*64 f]: gemm-out t for both GCN layers
    //  R2 [25.6MB]: h1 planes -> sn[E]+ebuf[E] int2 -> h5 planes
    //  R3 [12.8MB]: h2 planes -> g1 planes -> g2 planes
    //  whi/wlo, dinv, row, cnt, pos, bucketBase, bs
    float* bufT = (float*)d_ws;
    unsigned short* R2 = (unsigned short*)(bufT + (size_t)N * 64);
    unsigned short* h1h = R2;
    unsigned short* h1l = R2 + (size_t)N * 128;
    int2* sn   = (int2*)R2;
    int2* ebuf = sn + E;
    unsigned short* h5h = R2;
    unsigned short* h5l = R2 + (size_t)N * 128;
    unsigned short* R3 = R2 + (size_t)2 * N * 128;
    unsigned short* gh = R3;                       // h2 / g1 / g2 hi
    unsigned short* gl = R3 + (size_t)N * 64;      // h2 / g1 / g2 lo
    unsigned short* whi = R3 + (size_t)2 * N * 64;
    unsigned short* wlo = whi + 90112;
    float* dinv = (float*)(wlo + 90112);
    int*   row  = (int*)(dinv + N);                // N+1
    int*   cnt  = row + (N + 1);                   // NCNT
    int*   pos  = cnt + NCNT;                      // NCNT
    int*   bucketBase = pos + NCNT;                // NB+1
    int*   bs   = bucketBase + (NB + 1);           // 256

    const int gemmGrid = (N + 63) / 64;            // 782
    const int nBlkE    = (E + 255) / 256;          // 6250

    // weight pre-split (runs once, ~720KB traffic)
    WSplitArgs wa;
    const float* wsrc[6] = {enc1_w, enc2_w, gcn1_w, gcn2_w, dec1_w, dec2_w};
    const int    wsz[6]  = {32768, 8192, 4096, 4096, 8192, 32768};
    const int    woff[6] = {0, 32768, 40960, 45056, 49152, 57344};
    for (int l = 0; l < 6; ++l) {
        wa.src[l] = wsrc[l];
        wa.hi[l]  = whi + woff[l];
        wa.lo[l]  = wlo + woff[l];
        wa.n[l]   = wsz[l];
    }
    split_w<<<dim3(128, 6), 256, 0, stream>>>(wa);

    // encoder (enc1 splits fp32 x in regs; outputs are hi/lo planes)
    gemm_pp<256, 128, 1, true, true, 1><<<dim3(gemmGrid, 2), 128, 0, stream>>>(
        nullptr, nullptr, x, whi + woff[0], wlo + woff[0], enc1_b,
        nullptr, h1h, h1l, N);
    gemm_pp<128, 64, 1, true, false, 1><<<dim3(gemmGrid, 1), 128, 0, stream>>>(
        h1h, h1l, nullptr, whi + woff[1], wlo + woff[1], enc2_b,
        nullptr, gh, gl, N);

    // CSR build, zero global atomics (shared by both GCN layers)
    count_k<<<NBLK, 256, 0, stream>>>(ei, cnt, NB, E);
    scan1<<<NS, 256, 0, stream>>>(cnt, pos, bs, NCNT);
    scan_tops<<<1, 256, 0, stream>>>(bs, NS);
    scan2<<<NS, 256, 0, stream>>>(pos, bs, bucketBase, NCNT, NB, E);
    place_k<<<NBLK, 256, 0, stream>>>(ei, ew, pos, ebuf, NB, E);
    bucket_build<<<NB, 256, 0, stream>>>(ebuf, bucketBase, sn, row, dinv, N, E);
    scale_pay<<<nBlkE, 256, 0, stream>>>(sn, dinv, E);

    // GCN layer 1 (gemm -> fp32 t; agg -> planes over same R3 region)
    gemm_pp<64, 64, 0, false, false, 0><<<dim3(gemmGrid, 1), 128, 0, stream>>>(
        gh, gl, nullptr, whi + woff[2], wlo + woff[2], nullptr,
        bufT, nullptr, nullptr, N);
    gcn_agg<<<(N + 3) / 4, 256, 0, stream>>>(bufT, sn, row, dinv, gcn1_b, gh, gl, N);

    // GCN layer 2
    gemm_pp<64, 64, 0, false, false, 0><<<dim3(gemmGrid, 1), 128, 0, stream>>>(
        gh, gl, nullptr, whi + woff[3], wlo + woff[3], nullptr,
        bufT, nullptr, nullptr, N);
    gcn_agg<<<(N + 3) / 4, 256, 0, stream>>>(bufT, sn, row, dinv, gcn2_b, gh, gl, N);

    // decoder (h5 planes overwrite dead sn/ebuf region)
    gemm_pp<64, 128, 1, true, false, 1><<<dim3(gemmGrid, 2), 128, 0, stream>>>(
        gh, gl, nullptr, whi + woff[4], wlo + woff[4], dec1_b,
        nullptr, h5h, h5l, N);
    gemm_pp<128, 256, 2, true, false, 0><<<dim3(gemmGrid, 4), 128, 0, stream>>>(
        h5h, h5l, nullptr, whi + woff[5], wlo + woff[5], dec2_b,
        (float*)d_out, nullptr, nullptr, N);
}

// Round 8
// 465.311 us; speedup vs baseline: 1.0599x; 1.0599x over previous
//
#include <hip/hip_runtime.h>

// =====================================================================
// GraphAutoEncoder forward. GCN via CSR build + gather (R4 structure).
// R16 post-mortem: barrier-free reg GEMM had only ~2.3KB in flight per
// CU (need ~22KB for 6.3TB/s) -> 826 GB/s fetch, enc1 62us. R17: async
// A-staging via global_load_lds (in-flight bytes live in LDS, tracked
// by vmcnt, no VGPR cost). 2-phase: STAGE(next) -> compute(cur) ->
// __syncthreads (drains DMA). XOR-swizzle (row&7)<<4 applied to GLOBAL
// source + LDS read (DMA dest must stay linear); read = 2 lanes/bank.
// All-fp32 dataflow (planes dropped: same bytes, caused write scatter);
// split-bf16 3-MFMA in regs after LDS read (R14-16 numerics, passed).
// grid=(M/64, 782): feat-tiles fastest -> A-tile L2 reuse.
// =====================================================================

constexpr int NBLK = 128;           // scatter blocks (chunk = E/128)
constexpr int GRP  = NBLK / 8;      // block-groups per XCD residue

typedef __attribute__((ext_vector_type(8))) short bf16x8;
typedef __attribute__((ext_vector_type(4))) float f32x4;

__device__ inline void split2(float f0, float f1, unsigned& hp, unsigned& lp) {
    unsigned u0 = __float_as_uint(f0), u1 = __float_as_uint(f1);
    hp = (u1 & 0xFFFF0000u) | (u0 >> 16);
    float r0 = f0 - __uint_as_float(u0 & 0xFFFF0000u);
    float r1 = f1 - __uint_as_float(u1 & 0xFFFF0000u);
    lp = (__float_as_uint(r1) & 0xFFFF0000u) | (__float_as_uint(r0) >> 16);
}

struct Bf16Pair { bf16x8 h, l; };
__device__ inline Bf16Pair split8(float4 a, float4 b) {
    union { unsigned u[4]; bf16x8 v; } H, L;
    split2(a.x, a.y, H.u[0], L.u[0]);
    split2(a.z, a.w, H.u[1], L.u[1]);
    split2(b.x, b.y, H.u[2], L.u[2]);
    split2(b.z, b.w, H.u[3], L.u[3]);
    Bf16Pair p; p.h = H.v; p.l = L.v; return p;
}

__device__ __forceinline__ void dma16(const float* g, void* l) {
    __builtin_amdgcn_global_load_lds(
        (const __attribute__((address_space(1))) unsigned*)g,
        (__attribute__((address_space(3))) unsigned*)l, 16, 0, 0);
}

// ---------------- GEMM: C[:,foff:+64] = act(A @ W^T + b) -------------
// fp32 in/out. BM=64 nodes, BN=64 feats, KS=64, 256 thr = 4 waves
// (2Mx2N, wave tile 32x32). A staged async to LDS; W direct (L2-hot).
template <int K, int M, int ACT, bool BIAS>  // ACT: 0 none,1 relu,2 sigmoid
__global__ __launch_bounds__(256) void gemm_dma(const float* __restrict__ A,
                                                const float* __restrict__ W,
                                                const float* __restrict__ bias,
                                                float* __restrict__ C, int N) {
    static_assert(K % 64 == 0, "K%64");
    constexpr int KS = 64;
    __shared__ __align__(16) unsigned char Ab[2][16384];  // [64 rows][256B]

    const int tid      = threadIdx.x;
    const int lane     = tid & 63;
    const int wid      = tid >> 6;
    const int wm       = wid >> 1;
    const int wn       = wid & 1;
    const int fr       = lane & 15;
    const int fg       = lane >> 4;
    const int foff     = blockIdx.x * 64;
    const int nodeBase = blockIdx.y * 64;

    // async stage of A[nodeBase..+64][kc..kc+64) into Ab[buf], with the
    // XOR swizzle applied on the GLOBAL side (LDS dest linear, m173).
    auto STAGE = [&](int buf, int kc) {
#pragma unroll
        for (int c = 0; c < 4; ++c) {
            const int chunk = (wid * 4 + c) * 1024;      // wave-uniform
            const int s     = chunk + lane * 16;
            const int r     = s >> 8;                     // 0..63
            const int si    = (s & 255) ^ ((r & 7) << 4); // swizzled source byte
            int row = nodeBase + r;
            if (row >= N) row = N - 1;
            const float* gp = A + (size_t)row * K + kc + (si >> 2);
            dma16(gp, (char*)Ab[buf] + chunk);
        }
    };

    f32x4 acc[2][2];
#pragma unroll
    for (int mf = 0; mf < 2; ++mf)
#pragma unroll
        for (int nf = 0; nf < 2; ++nf) acc[mf][nf] = (f32x4)0.f;

    STAGE(0, 0);
    int cur = 0;
    for (int kc = 0; kc < K; kc += KS) {
        __syncthreads();                 // drains DMA of buf[cur]
        if (kc + KS < K) STAGE(cur ^ 1, kc + KS);

#pragma unroll
        for (int kf = 0; kf < 2; ++kf) {
            bf16x8 ah[2], al[2], bh[2], bl[2];
#pragma unroll
            for (int mf = 0; mf < 2; ++mf) {
                const int r  = wm * 32 + mf * 16 + fr;
                const int xr = (r & 7) << 4;
                const int ch = kf * 8 + fg * 2;           // 16B chunk index
                float4 f0 = *(const float4*)&Ab[cur][r * 256 + ((ch * 16) ^ xr)];
                float4 f1 = *(const float4*)&Ab[cur][r * 256 + (((ch + 1) * 16) ^ xr)];
                Bf16Pair p = split8(f0, f1);
                ah[mf] = p.h; al[mf] = p.l;
            }
#pragma unroll
            for (int nf = 0; nf < 2; ++nf) {
                const float* wp = W + (size_t)(foff + wn * 32 + nf * 16 + fr) * K
                                  + kc + kf * 32 + fg * 8;
                float4 g0 = *(const float4*)wp;
                float4 g1 = *(const float4*)(wp + 4);
                Bf16Pair p = split8(g0, g1);
                bh[nf] = p.h; bl[nf] = p.l;
            }
#pragma unroll
            for (int mf = 0; mf < 2; ++mf)
#pragma unroll
                for (int nf = 0; nf < 2; ++nf) {
                    acc[mf][nf] = __builtin_amdgcn_mfma_f32_16x16x32_bf16(
                        ah[mf], bh[nf], acc[mf][nf], 0, 0, 0);
                    acc[mf][nf] = __builtin_amdgcn_mfma_f32_16x16x32_bf16(
                        al[mf], bh[nf], acc[mf][nf], 0, 0, 0);
                    acc[mf][nf] = __builtin_amdgcn_mfma_f32_16x16x32_bf16(
                        ah[mf], bl[nf], acc[mf][nf], 0, 0, 0);
                }
        }
        cur ^= 1;
    }

    // epilogue: D[row=(lane>>4)*4+i][col=lane&15] per frag (verified R14-16)
#pragma unroll
    for (int nf = 0; nf < 2; ++nf) {
        const int feat = foff + wn * 32 + nf * 16 + fr;
        const float bv = BIAS ? bias[feat] : 0.f;
#pragma unroll
        for (int mf = 0; mf < 2; ++mf) {
            const int node0 = nodeBase + wm * 32 + mf * 16 + fg * 4;
#pragma unroll
            for (int i = 0; i < 4; ++i) {
                const int node = node0 + i;
                if (node < N) {
                    float x = acc[mf][nf][i] + bv;
                    if constexpr (ACT == 1) x = fmaxf(x, 0.f);
                    if constexpr (ACT == 2) x = 1.f / (1.f + __expf(-x));
                    C[(size_t)node * M + feat] = x;
                }
            }
        }
    }
}

// ---------------- CSR build: deterministic counting sort -------------

__global__ __launch_bounds__(256) void count_k(const int* __restrict__ ei,
                                               int* __restrict__ cnt,
                                               int NB, int E) {
    __shared__ int hist[784];
    const int tid = threadIdx.x;
    for (int i = tid; i < NB; i += 256) hist[i] = 0;
    __syncthreads();
    const int chunk = (E + NBLK - 1) / NBLK;
    const int lo = blockIdx.x * chunk;
    const int hi = min(lo + chunk, E);
    for (int e = lo + tid; e < hi; e += 256) {
        int d = ei[E + e];
        atomicAdd(&hist[d >> 6], 1);
    }
    __syncthreads();
    const int r = blockIdx.x & 7, g = blockIdx.x >> 3;
    for (int i = tid; i < NB; i += 256)
        cnt[i * NBLK + r * GRP + g] = hist[i];
}

__global__ __launch_bounds__(256) void scan1(const int* __restrict__ cnt,
                                             int* __restrict__ pos,
                                             int* __restrict__ bs, int n) {
    __shared__ int s[256];
    const int t = threadIdx.x;
    const int i0 = blockIdx.x * 512 + 2 * t;
    int c0 = (i0     < n) ? cnt[i0]     : 0;
    int c1 = (i0 + 1 < n) ? cnt[i0 + 1] : 0;
    int c = c0 + c1;
    s[t] = c;
    __syncthreads();
    for (int off = 1; off < 256; off <<= 1) {
        int v = (t >= off) ? s[t - off] : 0;
        __syncthreads();
        s[t] += v;
        __syncthreads();
    }
    int excl = s[t] - c;
    if (i0     < n) pos[i0]     = excl;
    if (i0 + 1 < n) pos[i0 + 1] = excl + c0;
    if (t == 255) bs[blockIdx.x] = s[255];
}

__global__ __launch_bounds__(256) void scan_tops(int* __restrict__ bs, int nb) {
    __shared__ int s[256];
    int t = threadIdx.x;
    int v = (t < nb) ? bs[t] : 0;
    s[t] = v;
    __syncthreads();
    for (int off = 1; off < 256; off <<= 1) {
        int u = (t >= off) ? s[t - off] : 0;
        __syncthreads();
        s[t] += u;
        __syncthreads();
    }
    if (t < nb) bs[t] = s[t] - v;
}

__global__ __launch_bounds__(256) void scan2(int* __restrict__ pos,
                                             const int* __restrict__ bs,
                                             int* __restrict__ bucketBase,
                                             int n, int NB, int E) {
    const int t = threadIdx.x;
    const int i0 = blockIdx.x * 512 + 2 * t;
    const int add = bs[blockIdx.x];
#pragma unroll
    for (int c = 0; c < 2; ++c) {
        int i = i0 + c;
        if (i < n) {
            int v = pos[i] + add;
            pos[i] = v;
            if ((i & (NBLK - 1)) == 0) bucketBase[i >> 7] = v;
        }
    }
    if (blockIdx.x == 0 && t == 0) bucketBase[NB] = E;
}

__global__ __launch_bounds__(256) void place_k(const int* __restrict__ ei,
                                               const float* __restrict__ w,
                                               const int* __restrict__ pos,
                                               int2* __restrict__ ebuf,
                                               int NB, int E) {
    __shared__ int cur[784];
    const int tid = threadIdx.x;
    const int r = blockIdx.x & 7, g = blockIdx.x >> 3;
    for (int i = tid; i < NB; i += 256) cur[i] = pos[i * NBLK + r * GRP + g];
    __syncthreads();
    const int chunk = (E + NBLK - 1) / NBLK;
    const int lo = blockIdx.x * chunk;
    const int hi = min(lo + chunk, E);
    for (int e = lo + tid; e < hi; e += 256) {
        int s = ei[e];
        int d = ei[E + e];
        float wv = w[e];
        int p = atomicAdd(&cur[d >> 6], 1);  // LDS atomic
        ebuf[p] = make_int2(s | ((d & 63) << 26), __float_as_int(wv));
    }
}

__global__ __launch_bounds__(256) void bucket_build(const int2* __restrict__ ebuf,
                                                    const int* __restrict__ bucketBase,
                                                    int2* __restrict__ sn,
                                                    int* __restrict__ row,
                                                    float* __restrict__ dinv,
                                                    int N, int E) {
    __shared__ int   lh[64];
    __shared__ float ldg[64];
    __shared__ int   sc[64];
    __shared__ int   lofs[64];
    const int tid  = threadIdx.x;
    const int base = bucketBase[blockIdx.x];
    const int end  = bucketBase[blockIdx.x + 1];

    if (tid < 64) { lh[tid] = 0; ldg[tid] = 0.f; }
    __syncthreads();
    for (int i = base + tid; i < end; i += 256) {
        int2 v = ebuf[i];
        int dl = ((unsigned)v.x) >> 26;
        atomicAdd(&lh[dl], 1);
        atomicAdd(&ldg[dl], __int_as_float(v.y));
    }
    __syncthreads();
    if (tid < 64) sc[tid] = lh[tid];
    __syncthreads();
    for (int off = 1; off < 64; off <<= 1) {
        int v = (tid < 64 && tid >= off) ? sc[tid - off] : 0;
        __syncthreads();
        if (tid < 64) sc[tid] += v;
        __syncthreads();
    }
    if (tid < 64) {
        int excl = sc[tid] - lh[tid];
        int d = (blockIdx.x << 6) + tid;
        if (d < N) {
            row[d]  = base + excl;
            dinv[d] = rsqrtf(fmaxf(1.0f + ldg[tid], 1e-12f));  // + self-loop
        }
        lofs[tid] = base + excl;
    }
    __syncthreads();
    for (int i = base + tid; i < end; i += 256) {
        int2 v = ebuf[i];
        unsigned u = (unsigned)v.x;
        int dl = u >> 26;
        int s  = u & 0x03FFFFFF;
        int p  = atomicAdd(&lofs[dl], 1);
        sn[p] = make_int2(s, v.y);
    }
    if (blockIdx.x == 0 && tid == 0) row[N] = E;
}

// payload.y <- w * dinv[src]
__global__ __launch_bounds__(256) void scale_pay(int2* __restrict__ sn,
                                                 const float* __restrict__ dinv,
                                                 int E) {
    int p = blockIdx.x * 256 + threadIdx.x;
    if (p < E) {
        int2 v = sn[p];
        sn[p] = make_int2(v.x, __float_as_int(__int_as_float(v.y) * dinv[v.x]));
    }
}

// ---------------- fused GCN aggregation (gather, no atomics) ---------
__global__ __launch_bounds__(256) void gcn_agg(const float* __restrict__ t,
                                               const int2* __restrict__ sn,
                                               const int* __restrict__ row,
                                               const float* __restrict__ dinv,
                                               const float* __restrict__ bias,
                                               float* __restrict__ out, int N) {
    const int lane = threadIdx.x & 63;
    int i = __builtin_amdgcn_readfirstlane((int)(blockIdx.x * 4) + (threadIdx.x >> 6));
    if (i >= N) return;
    float di   = dinv[i];
    float self = t[(size_t)i * 64 + lane];
    float acc  = 0.f;
    int p  = row[i];
    int pe = row[i + 1];
    for (; p + 4 <= pe; p += 4) {
        int2 v0 = sn[p];
        int2 v1 = sn[p + 1];
        int2 v2 = sn[p + 2];
        int2 v3 = sn[p + 3];
        acc += t[(size_t)v0.x * 64 + lane] * __int_as_float(v0.y);
        acc += t[(size_t)v1.x * 64 + lane] * __int_as_float(v1.y);
        acc += t[(size_t)v2.x * 64 + lane] * __int_as_float(v2.y);
        acc += t[(size_t)v3.x * 64 + lane] * __int_as_float(v3.y);
    }
    for (; p < pe; ++p) {
        int2 v = sn[p];
        acc += t[(size_t)v.x * 64 + lane] * __int_as_float(v.y);
    }
    float x = (acc + self * di) * di + bias[lane];
    out[(size_t)i * 64 + lane] = fmaxf(x, 0.f);
}

// =====================================================================
extern "C" void kernel_launch(void* const* d_in, const int* in_sizes, int n_in,
                              void* d_out, int out_size, void* d_ws, size_t ws_size,
                              hipStream_t stream) {
    const float* x      = (const float*)d_in[0];
    const int*   ei     = (const int*)d_in[1];   // int32 per harness contract
    const float* ew     = (const float*)d_in[2];
    const float* enc1_w = (const float*)d_in[3];
    const float* enc1_b = (const float*)d_in[4];
    const float* enc2_w = (const float*)d_in[5];
    const float* enc2_b = (const float*)d_in[6];
    const float* gcn1_w = (const float*)d_in[7];
    const float* gcn1_b = (const float*)d_in[8];
    const float* gcn2_w = (const float*)d_in[9];
    const float* gcn2_b = (const float*)d_in[10];
    const float* dec1_w = (const float*)d_in[11];
    const float* dec1_b = (const float*)d_in[12];
    const float* dec2_w = (const float*)d_in[13];
    const float* dec2_b = (const float*)d_in[14];

    const int N  = in_sizes[0] / 256;    // 50000
    const int E  = in_sizes[2];          // 1600000
    const int NB = (N + 63) / 64;        // 782 buckets
    const int NCNT = NB * NBLK;          // 100096 counters
    const int NS   = (NCNT + 511) / 512; // 196 scan blocks

    // workspace (~40 MB), lifetime-aliased (R4 layout):
    //  bufA [N*128 floats]: h1 -> { sn[E] int2 | ebuf[E] int2 (=bufC) } -> h5
    //  bufB [N*64]: h2/h3/h4 ; dinv[N]; row[N+1];
    //  cnt[NCNT]; pos[NCNT]; bucketBase[NB+1]; bs[256]
    float* ws   = (float*)d_ws;
    float* bufA = ws;
    int2*  sn   = (int2*)bufA;                  // E int2 (first half of bufA)
    float* bufC = bufA + (size_t)2 * E;         // N*64 floats (second half)
    int2*  ebuf = (int2*)bufC;                  // aliases bufC during build
    float* bufB = bufA + (size_t)N * 128;       // N*64
    float* dinv = bufB + (size_t)N * 64;        // N
    int*   row  = (int*)(dinv + N);             // N+1
    int*   cnt  = row + (N + 1);                // NCNT
    int*   pos  = cnt + NCNT;                   // NCNT
    int*   bucketBase = pos + NCNT;             // NB+1
    int*   bs   = bucketBase + (NB + 1);        // 256

    const int nodeTiles = (N + 63) / 64;        // 782
    const int nBlkE     = (E + 255) / 256;      // 6250

    // encoder
    gemm_dma<256, 128, 1, true><<<dim3(2, nodeTiles), 256, 0, stream>>>(
        x, enc1_w, enc1_b, bufA, N);
    gemm_dma<128, 64, 1, true><<<dim3(1, nodeTiles), 256, 0, stream>>>(
        bufA, enc2_w, enc2_b, bufB, N);

    // CSR build, zero global atomics (shared by both GCN layers)
    count_k<<<NBLK, 256, 0, stream>>>(ei, cnt, NB, E);
    scan1<<<NS, 256, 0, stream>>>(cnt, pos, bs, NCNT);
    scan_tops<<<1, 256, 0, stream>>>(bs, NS);
    scan2<<<NS, 256, 0, stream>>>(pos, bs, bucketBase, NCNT, NB, E);
    place_k<<<NBLK, 256, 0, stream>>>(ei, ew, pos, ebuf, NB, E);
    bucket_build<<<NB, 256, 0, stream>>>(ebuf, bucketBase, sn, row, dinv, N, E);
    scale_pay<<<nBlkE, 256, 0, stream>>>(sn, dinv, E);

    // GCN layer 1
    gemm_dma<64, 64, 0, false><<<dim3(1, nodeTiles), 256, 0, stream>>>(
        bufB, gcn1_w, nullptr, bufC, N);
    gcn_agg<<<(N + 3) / 4, 256, 0, stream>>>(bufC, sn, row, dinv, gcn1_b, bufB, N);

    // GCN layer 2
    gemm_dma<64, 64, 0, false><<<dim3(1, nodeTiles), 256, 0, stream>>>(
        bufB, gcn2_w, nullptr, bufC, N);
    gcn_agg<<<(N + 3) / 4, 256, 0, stream>>>(bufC, sn, row, dinv, gcn2_b, bufB, N);

    // decoder (bufA region free again: sn/ebuf dead after 2nd agg)
    gemm_dma<64, 128, 1, true><<<dim3(2, nodeTiles), 256, 0, stream>>>(
        bufB, dec1_w, dec1_b, bufA, N);
    gemm_dma<128, 256, 2, true><<<dim3(4, nodeTiles), 256, 0, stream>>>(
        bufA, dec2_w, dec2_b, (float*)d_out, N);
}

// Round 9
// 458.941 us; speedup vs baseline: 1.0746x; 1.0139x over previous
//
#include <hip/hip_runtime.h>

// =====================================================================
// GraphAutoEncoder forward. GCN via CSR build + gather (unchanged).
// R17 post-mortem: VALUBusy 34% / MfmaUtil 6.6% = 5:1 VALU:MFMA -- the
// split-bf16 conversion was re-paid on every use (W per block per kf,
// A per wn-wave). R18: pay the split once per element. (a) W pre-split
// once to global bf16 hi/lo planes -> B frags = two 16B loads, 0 VALU.
// (b) A split once during staging: global->reg->split->ds_write of
// bf16 planes; inner loop = ds_read + MFMA only. LDS [64][72] ushort
// (stride 144B = 16 mod 128 -> every 8-lane pass covers all 32 banks,
// write AND read conflict-free). Single buffer, 18.4KB -> ~6-8 blk/CU;
// next tile in-flight in VGPRs during compute. (c) bijective XCD
// swizzle (m204): feat-tiles of one node-tile share an XCD L2.
// =====================================================================

constexpr int NBLK = 128;           // scatter blocks (chunk = E/128)
constexpr int GRP  = NBLK / 8;      // block-groups per XCD residue

typedef __attribute__((ext_vector_type(8))) short bf16x8;
typedef __attribute__((ext_vector_type(4))) float f32x4;

__device__ inline void split2(float f0, float f1, unsigned& hp, unsigned& lp) {
    unsigned u0 = __float_as_uint(f0), u1 = __float_as_uint(f1);
    hp = (u1 & 0xFFFF0000u) | (u0 >> 16);
    float r0 = f0 - __uint_as_float(u0 & 0xFFFF0000u);
    float r1 = f1 - __uint_as_float(u1 & 0xFFFF0000u);
    lp = (__float_as_uint(r1) & 0xFFFF0000u) | (__float_as_uint(r0) >> 16);
}

struct Bf16Pair { bf16x8 h, l; };
__device__ inline Bf16Pair split8(float4 a, float4 b) {
    union { unsigned u[4]; bf16x8 v; } H, L;
    split2(a.x, a.y, H.u[0], L.u[0]);
    split2(a.z, a.w, H.u[1], L.u[1]);
    split2(b.x, b.y, H.u[2], L.u[2]);
    split2(b.z, b.w, H.u[3], L.u[3]);
    Bf16Pair p; p.h = H.v; p.l = L.v; return p;
}

// ---------------- weight pre-split: fp32 -> bf16 hi/lo planes --------
struct WSplitArgs {
    const float* src[6];
    unsigned short* hi[6];
    unsigned short* lo[6];
    int n[6];
};
__global__ __launch_bounds__(256) void split_w(WSplitArgs a) {
    const int L = blockIdx.y;
    const int i = blockIdx.x * 256 + threadIdx.x;
    if (i < a.n[L]) {
        float f = a.src[L][i];
        unsigned u = __float_as_uint(f);
        float r = f - __uint_as_float(u & 0xFFFF0000u);
        a.hi[L][i] = (unsigned short)(u >> 16);
        a.lo[L][i] = (unsigned short)(__float_as_uint(r) >> 16);
    }
}

// ---------------- GEMM: C[:,foff:+64] = act(A @ W^T + b) -------------
// fp32 A in, fp32 C out. W as pre-split planes. BM=64, BN=64, KS=64.
// 256 thr = 4 waves (2Mx2N, wave tile 32x32). grid (M/64, ceil(N/64)).
template <int K, int M, int ACT, bool BIAS>  // ACT: 0 none,1 relu,2 sigmoid
__global__ __launch_bounds__(256) void gemm_sp(const float* __restrict__ A,
                                               const unsigned short* __restrict__ Whp,
                                               const unsigned short* __restrict__ Wlp,
                                               const float* __restrict__ bias,
                                               float* __restrict__ C, int N) {
    static_assert(K % 64 == 0, "K%64");
    constexpr int KS = 64;
    // stride 72 ushorts = 144B == 16 (mod 128): conflict-free r/w
    __shared__ __align__(16) unsigned short Ah[64][72];
    __shared__ __align__(16) unsigned short Al[64][72];

    // bijective XCD swizzle (m204): contiguous wgid chunk per XCD
    const int gx  = gridDim.x;
    const int nwg = gx * gridDim.y;
    {
    }
    const int o    = blockIdx.y * gx + blockIdx.x;
    const int xcd  = o & 7;
    const int idx  = o >> 3;
    const int q    = nwg >> 3, rr = nwg & 7;
    const int wgid = (xcd < rr ? xcd * (q + 1) : rr * (q + 1) + (xcd - rr) * q) + idx;
    const int foff     = (wgid % gx) * 64;
    const int nodeBase = (wgid / gx) * 64;

    const int tid  = threadIdx.x;
    const int lane = tid & 63;
    const int wid  = tid >> 6;
    const int wm   = wid >> 1;
    const int wn   = wid & 1;
    const int fr   = lane & 15;
    const int fg   = lane >> 4;

    // staging coords: 4 threads per row, 16 floats each
    const int srow = tid >> 2;
    const int sc0  = (tid & 3) * 16;
    int grow = nodeBase + srow;
    if (grow >= N) grow = N - 1;
    const float* aptr = A + (size_t)grow * K + sc0;

    float4 av[4];
#pragma unroll
    for (int i = 0; i < 4; ++i) av[i] = *(const float4*)(aptr + i * 4);

    f32x4 acc[2][2];
#pragma unroll
    for (int mf = 0; mf < 2; ++mf)
#pragma unroll
        for (int nf = 0; nf < 2; ++nf) acc[mf][nf] = (f32x4)0.f;

    for (int kc = 0; kc < K; kc += KS) {
        // split once, commit bf16 planes to LDS
        {
            Bf16Pair p0 = split8(av[0], av[1]);
            Bf16Pair p1 = split8(av[2], av[3]);
            *(bf16x8*)&Ah[srow][sc0]     = p0.h;
            *(bf16x8*)&Ah[srow][sc0 + 8] = p1.h;
            *(bf16x8*)&Al[srow][sc0]     = p0.l;
            *(bf16x8*)&Al[srow][sc0 + 8] = p1.l;
        }
        __syncthreads();

        // prefetch next A tile into regs (drains during compute)
        if (kc + KS < K) {
#pragma unroll
            for (int i = 0; i < 4; ++i)
                av[i] = *(const float4*)(aptr + kc + KS + i * 4);
        }

#pragma unroll
        for (int kf = 0; kf < 2; ++kf) {
            const int kcol = kf * 32 + fg * 8;
            bf16x8 ah[2], al[2], bh[2], bl[2];
#pragma unroll
            for (int mf = 0; mf < 2; ++mf) {
                const int r = wm * 32 + mf * 16 + fr;
                ah[mf] = *(const bf16x8*)&Ah[r][kcol];
                al[mf] = *(const bf16x8*)&Al[r][kcol];
            }
#pragma unroll
            for (int nf = 0; nf < 2; ++nf) {
                const size_t wo = (size_t)(foff + wn * 32 + nf * 16 + fr) * K
                                  + kc + kcol;
                bh[nf] = *(const bf16x8*)(Whp + wo);
                bl[nf] = *(const bf16x8*)(Wlp + wo);
            }
#pragma unroll
            for (int mf = 0; mf < 2; ++mf)
#pragma unroll
                for (int nf = 0; nf < 2; ++nf) {
                    acc[mf][nf] = __builtin_amdgcn_mfma_f32_16x16x32_bf16(
                        ah[mf], bh[nf], acc[mf][nf], 0, 0, 0);
                    acc[mf][nf] = __builtin_amdgcn_mfma_f32_16x16x32_bf16(
                        al[mf], bh[nf], acc[mf][nf], 0, 0, 0);
                    acc[mf][nf] = __builtin_amdgcn_mfma_f32_16x16x32_bf16(
                        ah[mf], bl[nf], acc[mf][nf], 0, 0, 0);
                }
        }
        __syncthreads();
    }

    // epilogue: D[row=(lane>>4)*4+i][col=lane&15] per frag (R14-17 verified)
#pragma unroll
    for (int nf = 0; nf < 2; ++nf) {
        const int feat = foff + wn * 32 + nf * 16 + fr;
        const float bv = BIAS ? bias[feat] : 0.f;
#pragma unroll
        for (int mf = 0; mf < 2; ++mf) {
            const int node0 = nodeBase + wm * 32 + mf * 16 + fg * 4;
#pragma unroll
            for (int i = 0; i < 4; ++i) {
                const int node = node0 + i;
                if (node < N) {
                    float x = acc[mf][nf][i] + bv;
                    if constexpr (ACT == 1) x = fmaxf(x, 0.f);
                    if constexpr (ACT == 2) x = 1.f / (1.f + __expf(-x));
                    C[(size_t)node * M + feat] = x;
                }
            }
        }
    }
}

// ---------------- CSR build: deterministic counting sort -------------

__global__ __launch_bounds__(256) void count_k(const int* __restrict__ ei,
                                               int* __restrict__ cnt,
                                               int NB, int E) {
    __shared__ int hist[784];
    const int tid = threadIdx.x;
    for (int i = tid; i < NB; i += 256) hist[i] = 0;
    __syncthreads();
    const int chunk = (E + NBLK - 1) / NBLK;
    const int lo = blockIdx.x * chunk;
    const int hi = min(lo + chunk, E);
    for (int e = lo + tid; e < hi; e += 256) {
        int d = ei[E + e];
        atomicAdd(&hist[d >> 6], 1);
    }
    __syncthreads();
    const int r = blockIdx.x & 7, g = blockIdx.x >> 3;
    for (int i = tid; i < NB; i += 256)
        cnt[i * NBLK + r * GRP + g] = hist[i];
}

__global__ __launch_bounds__(256) void scan1(const int* __restrict__ cnt,
                                             int* __restrict__ pos,
                                             int* __restrict__ bs, int n) {
    __shared__ int s[256];
    const int t = threadIdx.x;
    const int i0 = blockIdx.x * 512 + 2 * t;
    int c0 = (i0     < n) ? cnt[i0]     : 0;
    int c1 = (i0 + 1 < n) ? cnt[i0 + 1] : 0;
    int c = c0 + c1;
    s[t] = c;
    __syncthreads();
    for (int off = 1; off < 256; off <<= 1) {
        int v = (t >= off) ? s[t - off] : 0;
        __syncthreads();
        s[t] += v;
        __syncthreads();
    }
    int excl = s[t] - c;
    if (i0     < n) pos[i0]     = excl;
    if (i0 + 1 < n) pos[i0 + 1] = excl + c0;
    if (t == 255) bs[blockIdx.x] = s[255];
}

__global__ __launch_bounds__(256) void scan_tops(int* __restrict__ bs, int nb) {
    __shared__ int s[256];
    int t = threadIdx.x;
    int v = (t < nb) ? bs[t] : 0;
    s[t] = v;
    __syncthreads();
    for (int off = 1; off < 256; off <<= 1) {
        int u = (t >= off) ? s[t - off] : 0;
        __syncthreads();
        s[t] += u;
        __syncthreads();
    }
    if (t < nb) bs[t] = s[t] - v;
}

__global__ __launch_bounds__(256) void scan2(int* __restrict__ pos,
                                             const int* __restrict__ bs,
                                             int* __restrict__ bucketBase,
                                             int n, int NB, int E) {
    const int t = threadIdx.x;
    const int i0 = blockIdx.x * 512 + 2 * t;
    const int add = bs[blockIdx.x];
#pragma unroll
    for (int c = 0; c < 2; ++c) {
        int i = i0 + c;
        if (i < n) {
            int v = pos[i] + add;
            pos[i] = v;
            if ((i & (NBLK - 1)) == 0) bucketBase[i >> 7] = v;
        }
    }
    if (blockIdx.x == 0 && t == 0) bucketBase[NB] = E;
}

__global__ __launch_bounds__(256) void place_k(const int* __restrict__ ei,
                                               const float* __restrict__ w,
                                               const int* __restrict__ pos,
                                               int2* __restrict__ ebuf,
                                               int NB, int E) {
    __shared__ int cur[784];
    const int tid = threadIdx.x;
    const int r = blockIdx.x & 7, g = blockIdx.x >> 3;
    for (int i = tid; i < NB; i += 256) cur[i] = pos[i * NBLK + r * GRP + g];
    __syncthreads();
    const int chunk = (E + NBLK - 1) / NBLK;
    const int lo = blockIdx.x * chunk;
    const int hi = min(lo + chunk, E);
    for (int e = lo + tid; e < hi; e += 256) {
        int s = ei[e];
        int d = ei[E + e];
        float wv = w[e];
        int p = atomicAdd(&cur[d >> 6], 1);  // LDS atomic
        ebuf[p] = make_int2(s | ((d & 63) << 26), __float_as_int(wv));
    }
}

__global__ __launch_bounds__(256) void bucket_build(const int2* __restrict__ ebuf,
                                                    const int* __restrict__ bucketBase,
                                                    int2* __restrict__ sn,
                                                    int* __restrict__ row,
                                                    float* __restrict__ dinv,
                                                    int N, int E) {
    __shared__ int   lh[64];
    __shared__ float ldg[64];
    __shared__ int   sc[64];
    __shared__ int   lofs[64];
    const int tid  = threadIdx.x;
    const int base = bucketBase[blockIdx.x];
    const int end  = bucketBase[blockIdx.x + 1];

    if (tid < 64) { lh[tid] = 0; ldg[tid] = 0.f; }
    __syncthreads();
    for (int i = base + tid; i < end; i += 256) {
        int2 v = ebuf[i];
        int dl = ((unsigned)v.x) >> 26;
        atomicAdd(&lh[dl], 1);
        atomicAdd(&ldg[dl], __int_as_float(v.y));
    }
    __syncthreads();
    if (tid < 64) sc[tid] = lh[tid];
    __syncthreads();
    for (int off = 1; off < 64; off <<= 1) {
        int v = (tid < 64 && tid >= off) ? sc[tid - off] : 0;
        __syncthreads();
        if (tid < 64) sc[tid] += v;
        __syncthreads();
    }
    if (tid < 64) {
        int excl = sc[tid] - lh[tid];
        int d = (blockIdx.x << 6) + tid;
        if (d < N) {
            row[d]  = base + excl;
            dinv[d] = rsqrtf(fmaxf(1.0f + ldg[tid], 1e-12f));  // + self-loop
        }
        lofs[tid] = base + excl;
    }
    __syncthreads();
    for (int i = base + tid; i < end; i += 256) {
        int2 v = ebuf[i];
        unsigned u = (unsigned)v.x;
        int dl = u >> 26;
        int s  = u & 0x03FFFFFF;
        int p  = atomicAdd(&lofs[dl], 1);
        sn[p] = make_int2(s, v.y);
    }
    if (blockIdx.x == 0 && tid == 0) row[N] = E;
}

// payload.y <- w * dinv[src]
__global__ __launch_bounds__(256) void scale_pay(int2* __restrict__ sn,
                                                 const float* __restrict__ dinv,
                                                 int E) {
    int p = blockIdx.x * 256 + threadIdx.x;
    if (p < E) {
        int2 v = sn[p];
        sn[p] = make_int2(v.x, __float_as_int(__int_as_float(v.y) * dinv[v.x]));
    }
}

// ---------------- fused GCN aggregation (gather, no atomics) ---------
__global__ __launch_bounds__(256) void gcn_agg(const float* __restrict__ t,
                                               const int2* __restrict__ sn,
                                               const int* __restrict__ row,
                                               const float* __restrict__ dinv,
                                               const float* __restrict__ bias,
                                               float* __restrict__ out, int N) {
    const int lane = threadIdx.x & 63;
    int i = __builtin_amdgcn_readfirstlane((int)(blockIdx.x * 4) + (threadIdx.x >> 6));
    if (i >= N) return;
    float di   = dinv[i];
    float self = t[(size_t)i * 64 + lane];
    float acc  = 0.f;
    int p  = row[i];
    int pe = row[i + 1];
    for (; p + 4 <= pe; p += 4) {
        int2 v0 = sn[p];
        int2 v1 = sn[p + 1];
        int2 v2 = sn[p + 2];
        int2 v3 = sn[p + 3];
        acc += t[(size_t)v0.x * 64 + lane] * __int_as_float(v0.y);
        acc += t[(size_t)v1.x * 64 + lane] * __int_as_float(v1.y);
        acc += t[(size_t)v2.x * 64 + lane] * __int_as_float(v2.y);
        acc += t[(size_t)v3.x * 64 + lane] * __int_as_float(v3.y);
    }
    for (; p < pe; ++p) {
        int2 v = sn[p];
        acc += t[(size_t)v.x * 64 + lane] * __int_as_float(v.y);
    }
    float x = (acc + self * di) * di + bias[lane];
    out[(size_t)i * 64 + lane] = fmaxf(x, 0.f);
}

// =====================================================================
extern "C" void kernel_launch(void* const* d_in, const int* in_sizes, int n_in,
                              void* d_out, int out_size, void* d_ws, size_t ws_size,
                              hipStream_t stream) {
    const float* x      = (const float*)d_in[0];
    const int*   ei     = (const int*)d_in[1];   // int32 per harness contract
    const float* ew     = (const float*)d_in[2];
    const float* enc1_w = (const float*)d_in[3];
    const float* enc1_b = (const float*)d_in[4];
    const float* enc2_w = (const float*)d_in[5];
    const float* enc2_b = (const float*)d_in[6];
    const float* gcn1_w = (const float*)d_in[7];
    const float* gcn1_b = (const float*)d_in[8];
    const float* gcn2_w = (const float*)d_in[9];
    const float* gcn2_b = (const float*)d_in[10];
    const float* dec1_w = (const float*)d_in[11];
    const float* dec1_b = (const float*)d_in[12];
    const float* dec2_w = (const float*)d_in[13];
    const float* dec2_b = (const float*)d_in[14];

    const int N  = in_sizes[0] / 256;    // 50000
    const int E  = in_sizes[2];          // 1600000
    const int NB = (N + 63) / 64;        // 782 buckets
    const int NCNT = NB * NBLK;          // 100096 counters
    const int NS   = (NCNT + 511) / 512; // 196 scan blocks

    // workspace (~41 MB), lifetime-aliased (R4 layout + W planes):
    //  bufA [N*128 floats]: h1 -> { sn[E] int2 | ebuf[E] int2 (=bufC) } -> h5
    //  bufB [N*64]: h2/h3/h4 ; dinv[N]; row[N+1];
    //  cnt[NCNT]; pos[NCNT]; bucketBase[NB+1]; bs[256]; whi/wlo planes
    float* ws   = (float*)d_ws;
    float* bufA = ws;
    int2*  sn   = (int2*)bufA;                  // E int2 (first half of bufA)
    float* bufC = bufA + (size_t)2 * E;         // N*64 floats (second half)
    int2*  ebuf = (int2*)bufC;                  // aliases bufC during build
    float* bufB = bufA + (size_t)N * 128;       // N*64
    float* dinv = bufB + (size_t)N * 64;        // N
    int*   row  = (int*)(dinv + N);             // N+1
    int*   cnt  = row + (N + 1);                // NCNT
    int*   pos  = cnt + NCNT;                   // NCNT
    int*   bucketBase = pos + NCNT;             // NB+1
    int*   bs   = bucketBase + (NB + 1);        // 256
    unsigned short* whi = (unsigned short*)(bs + 256);  // 90112 ushorts
    unsigned short* wlo = whi + 90112;

    const int nodeTiles = (N + 63) / 64;        // 782
    const int nBlkE     = (E + 255) / 256;      // 6250

    // weight pre-split (runs once, ~720KB traffic)
    WSplitArgs wa;
    const float* wsrc[6] = {enc1_w, enc2_w, gcn1_w, gcn2_w, dec1_w, dec2_w};
    const int    wsz[6]  = {32768, 8192, 4096, 4096, 8192, 32768};
    const int    woff[6] = {0, 32768, 40960, 45056, 49152, 57344};
    for (int l = 0; l < 6; ++l) {
        wa.src[l] = wsrc[l];
        wa.hi[l]  = whi + woff[l];
        wa.lo[l]  = wlo + woff[l];
        wa.n[l]   = wsz[l];
    }
    split_w<<<dim3(128, 6), 256, 0, stream>>>(wa);

    // encoder
    gemm_sp<256, 128, 1, true><<<dim3(2, nodeTiles), 256, 0, stream>>>(
        x, whi + woff[0], wlo + woff[0], enc1_b, bufA, N);
    gemm_sp<128, 64, 1, true><<<dim3(1, nodeTiles), 256, 0, stream>>>(
        bufA, whi + woff[1], wlo + woff[1], enc2_b, bufB, N);

    // CSR build, zero global atomics (shared by both GCN layers)
    count_k<<<NBLK, 256, 0, stream>>>(ei, cnt, NB, E);
    scan1<<<NS, 256, 0, stream>>>(cnt, pos, bs, NCNT);
    scan_tops<<<1, 256, 0, stream>>>(bs, NS);
    scan2<<<NS, 256, 0, stream>>>(pos, bs, bucketBase, NCNT, NB, E);
    place_k<<<NBLK, 256, 0, stream>>>(ei, ew, pos, ebuf, NB, E);
    bucket_build<<<NB, 256, 0, stream>>>(ebuf, bucketBase, sn, row, dinv, N, E);
    scale_pay<<<nBlkE, 256, 0, stream>>>(sn, dinv, E);

    // GCN layer 1
    gemm_sp<64, 64, 0, false><<<dim3(1, nodeTiles), 256, 0, stream>>>(
        bufB, whi + woff[2], wlo + woff[2], nullptr, bufC, N);
    gcn_agg<<<(N + 3) / 4, 256, 0, stream>>>(bufC, sn, row, dinv, gcn1_b, bufB, N);

    // GCN layer 2
    gemm_sp<64, 64, 0, false><<<dim3(1, nodeTiles), 256, 0, stream>>>(
        bufB, whi + woff[3], wlo + woff[3], nullptr, bufC, N);
    gcn_agg<<<(N + 3) / 4, 256, 0, stream>>>(bufC, sn, row, dinv, gcn2_b, bufB, N);

    // decoder (bufA region free again: sn/ebuf dead after 2nd agg)
    gemm_sp<64, 128, 1, true><<<dim3(2, nodeTiles), 256, 0, stream>>>(
        bufB, whi + woff[4], wlo + woff[4], dec1_b, bufA, N);
    gemm_sp<128, 256, 2, true><<<dim3(4, nodeTiles), 256, 0, stream>>>(
        bufA, whi + woff[5], wlo + woff[5], dec2_b, (float*)d_out, N);
}